// Round 9
// baseline (263.263 us; speedup 1.0000x reference)
//
#include <hip/hip_runtime.h>
#include <cstddef>

typedef __fp16 f16x8 __attribute__((ext_vector_type(8)));
typedef float f32x4 __attribute__((ext_vector_type(4)));
typedef unsigned int uint32;
typedef unsigned short ushort;

constexpr int S = 64, MSG = 32, CH = 73;

// frag-linear f16 weight tiles in ws. One tile = 16 cols x 32 k = 64 lanes x 8 f16.
constexpr int FC1_OFF = 0;          // 12 tiles (t0..2 x f0..3)  K=96 (80 real + bias@80)
constexpr int ATT_OFF = 12 * 512;   // 6 tiles  (t0..2 x f0..1)  K=96 (73 real + bias@73)
constexpr int FC2_OFF = 18 * 512;   // 12 tiles (t0..2 x f0..3)  K=96 exact (bias separate)
constexpr int FC3_OFF = 30 * 512;   // 4 tiles  (t0..1 x f0..1)  K=64 exact (bias separate)
constexpr int WS_ELEMS = 34 * 512;  // 17408 ushort = 34816 B

__global__ void prep_pack(const float* __restrict__ W1, const float* __restrict__ b1,
                          const float* __restrict__ Wa, const float* __restrict__ ba,
                          const float* __restrict__ W2, const float* __restrict__ W3,
                          ushort* __restrict__ wsf) {
  int idx = blockIdx.x * 256 + threadIdx.x;
  if (idx >= WS_ELEMS) return;
  int tile = idx >> 9;
  int lane = (idx >> 3) & 63;
  int e = idx & 7;
  int jloc = lane & 15;
  int kloc = ((lane >> 4) << 3) + e;  // B-frag: lane holds B[k][col=lane&15], k=(lane>>4)*8+e
  float v = 0.f;
  if (tile < 12) {                       // W1 [64][80]
    int t = tile >> 2, f = tile & 3;
    int j = f * 16 + jloc, k = t * 32 + kloc;
    v = (k < 80) ? W1[j * 80 + k] : (k == 80 ? b1[j] : 0.f);
  } else if (tile < 18) {                // Wa [32][73]
    int q = tile - 12, t = q >> 1, f = q & 1;
    int j = f * 16 + jloc, k = t * 32 + kloc;
    v = (k < 73) ? Wa[j * 73 + k] : (k == 73 ? ba[j] : 0.f);
  } else if (tile < 30) {                // W2 [64][96]
    int q = tile - 18, t = q >> 2, f = q & 3;
    int j = f * 16 + jloc, k = t * 32 + kloc;
    v = W2[j * 96 + k];
  } else {                               // W3 [32][64]
    int q = tile - 30, t = q >> 1, f = q & 1;
    int j = f * 16 + jloc, k = t * 32 + kloc;
    v = W3[j * 64 + k];
  }
  union { __fp16 h; ushort s; } cv;
  cv.h = (__fp16)v;
  wsf[idx] = cv.s;
}

__device__ __forceinline__ f32x4 mf(f16x8 a, f16x8 b, f32x4 c) {
  return __builtin_amdgcn_mfma_f32_16x16x32_f16(a, b, c, 0, 0, 0);
}
__device__ __forceinline__ uint32 pku(float a, float b) {
  auto r = __builtin_amdgcn_cvt_pkrtz(a, b);
  union { decltype(r) f; uint32 u; } v; v.f = r; return v.u;
}
__device__ __forceinline__ f16x8 packA(const float* f) {
  union { uint32 u[4]; f16x8 h; } r;
  r.u[0] = pku(f[0], f[1]); r.u[1] = pku(f[2], f[3]);
  r.u[2] = pku(f[4], f[5]); r.u[3] = pku(f[6], f[7]);
  return r.h;
}
__device__ __forceinline__ f16x8 packA2(float4 a, float4 b) {
  union { uint32 u[4]; f16x8 h; } r;
  r.u[0] = pku(a.x, a.y); r.u[1] = pku(a.z, a.w);
  r.u[2] = pku(b.x, b.y); r.u[3] = pku(b.z, b.w);
  return r.h;
}
__device__ __forceinline__ float fast_tanh(float v) {
  v = fminf(15.f, fmaxf(-15.f, v));
  float t = __expf(2.f * v);
  return (t - 1.f) * __builtin_amdgcn_rcpf(t + 1.f);
}

constexpr int HT_LD = 104;  // f16 stride; 208 B (16B-aligned rows)
constexpr int H2_LD = 72;   // f16 stride; 144 B
// per-block smem: hbuf 4w x 3328 B = 13312; then per-wave union region 4672 B
// (csb during attention | h2buf after fc2) x 4w = 18688. total 32000 B.
constexpr int HBUF_B = 3328;
constexpr int UNION_OFF = 13312;
constexpr int UNION_B = 4672;
constexpr int SMEM_B = 32000;

__launch_bounds__(256)
__global__ void critic_mfma_kernel(
    const float* __restrict__ x, const float* __restrict__ u,
    const float* __restrict__ cs, const float* __restrict__ m,
    const float* __restrict__ b2, const float* __restrict__ b3,
    const ushort* __restrict__ wsf, float* __restrict__ out, int n) {
  __shared__ __attribute__((aligned(16))) unsigned char smem[SMEM_B];

  const int wave = threadIdx.x >> 6;
  const int lane = threadIdx.x & 63;
  const int lm = lane & 15;
  const int lq = lane >> 4;

  const int tiles = n >> 4;              // 16-row tiles
  const int wslots = gridDim.x * 4;      // wave slots in grid
  const int tbase = blockIdx.x * 4 + wave;
  if (tbase >= tiles) return;            // no barriers anywhere -> safe

  __fp16* __restrict__ ht = reinterpret_cast<__fp16*>(smem + wave * HBUF_B);
  float* __restrict__ csw = reinterpret_cast<float*>(smem + UNION_OFF + wave * UNION_B);
  __fp16* __restrict__ h2t = reinterpret_cast<__fp16*>(smem + UNION_OFF + wave * UNION_B);

  auto ldB = [&](int off_tile) -> f16x8 {
    return *reinterpret_cast<const f16x8*>(wsf + off_tile + lane * 8);
  };

  f16x8 wa[6];
#pragma unroll
  for (int i = 0; i < 6; ++i) wa[i] = ldB(ATT_OFF + i * 512);

  // ---- depth-2 cs staging register sets + depth-1 m sets -------------------
  float4 A0, A1, A2, A3, A4, B0, B1, B2, B3, B4;
  float MA[8], MB[8];
  float4 xva, xvb, xvc, xvd, uva, uvb;

  auto issueCsA = [&](int row16) {  // row16: first att-row of 16-row chunk
    const float4* __restrict__ src =
        reinterpret_cast<const float4*>(cs + (size_t)row16 * CH);
    A0 = src[lane];       A1 = src[64 + lane];
    A2 = src[128 + lane]; A3 = src[192 + lane];
    if (lane < 36) A4 = src[256 + lane];
  };
  auto issueCsB = [&](int row16) {
    const float4* __restrict__ src =
        reinterpret_cast<const float4*>(cs + (size_t)row16 * CH);
    B0 = src[lane];       B1 = src[64 + lane];
    B2 = src[128 + lane]; B3 = src[192 + lane];
    if (lane < 36) B4 = src[256 + lane];
  };
  auto commitA = [&]() {
    float4* __restrict__ dst = reinterpret_cast<float4*>(csw);
    dst[lane] = A0;       dst[64 + lane] = A1;
    dst[128 + lane] = A2; dst[192 + lane] = A3;
    if (lane < 36) dst[256 + lane] = A4;
  };
  auto commitB = [&]() {
    float4* __restrict__ dst = reinterpret_cast<float4*>(csw);
    dst[lane] = B0;       dst[64 + lane] = B1;
    dst[128 + lane] = B2; dst[192 + lane] = B3;
    if (lane < 36) dst[256 + lane] = B4;
  };
  auto issueM = [&](float* MR, int r0, int g) {
    const float* __restrict__ mrow = m + (size_t)(r0 + 4 * g + lq) * 128;
#pragma unroll
    for (int c = 0; c < 4; ++c) {
      MR[c * 2 + 0] = mrow[c * 32 + lm];
      MR[c * 2 + 1] = mrow[c * 32 + lm + 16];
    }
  };
  auto issueXU = [&](int r0) {
    const float4* __restrict__ xrow4 =
        reinterpret_cast<const float4*>(x + (size_t)(r0 + lm) * S);
    xva = xrow4[2 * lq]; xvb = xrow4[2 * lq + 1];
    xvc = xrow4[8 + 2 * lq]; xvd = xrow4[9 + 2 * lq];
    const int uq = (lq < 2) ? lq : 0;  // clamp: lanes lq>=2 don't use u
    const float4* __restrict__ urow4 =
        reinterpret_cast<const float4*>(u + (size_t)(r0 + lm) * 16);
    uva = urow4[2 * uq]; uvb = urow4[2 * uq + 1];
  };

  // attention chunk compute (g may be runtime; all reg arrays static-indexed)
  auto attnBody = [&](int r0, int g, const float* MR) {
    const float* __restrict__ crow = csw + lm * CH;
    f32x4 zac[2] = {{0.f, 0.f, 0.f, 0.f}, {0.f, 0.f, 0.f, 0.f}};
#pragma unroll
    for (int tt = 0; tt < 3; ++tt) {
      float f[8];
      const int kbase = tt * 32 + lq * 8;
#pragma unroll
      for (int e = 0; e < 8; ++e) {
        int k = kbase + e;
        f[e] = (k < 73) ? crow[k] : (k == 73 ? 1.f : 0.f);
      }
      f16x8 af = packA(f);
      zac[0] = mf(af, wa[tt * 2 + 0], zac[0]);
      zac[1] = mf(af, wa[tt * 2 + 1], zac[1]);
    }
#pragma unroll
    for (int f = 0; f < 2; ++f) {
      const int j = lm + 16 * f;
      float e0 = __expf(zac[f][0]);
      float e1 = __expf(zac[f][1]);
      float e2 = __expf(zac[f][2]);
      float e3 = __expf(zac[f][3]);
      float den = (e0 + e1) + (e2 + e3);
      float num = fmaf(MR[0 + f], e0,
                  fmaf(MR[2 + f], e1,
                  fmaf(MR[4 + f], e2, MR[6 + f] * e3)));
      float mg = num * __builtin_amdgcn_rcpf(den);
      ht[(4 * g + lq) * HT_LD + 64 + j] = (__fp16)fast_tanh(mg);
    }
  };

  const int r0_0 = tbase << 4;
  const int ntile = tbase + wslots;
  const bool has2 = ntile < tiles;
  const int r0_1 = has2 ? (ntile << 4) : r0_0;

  // prologue: chunk0+chunk1 cs, chunk0 m, tile0 xu
  issueCsA(r0_0 * 4);
  issueM(MA, r0_0, 0);
  issueCsB(r0_0 * 4 + 16);
  issueXU(r0_0);

  for (int t = 0; t < 2; ++t) {
    if (t == 1 && !has2) break;          // wave-uniform
    const int r0 = t ? r0_1 : r0_0;
    const bool pn = (t == 0) && has2;

    // ============ Attention: 4 chunks, depth-2 cs / depth-1 m pipeline =======
#pragma unroll
    for (int g = 0; g < 4; ++g) {
      // commit chunk g (loaded 2 chunks ago -> fully landed)
      if ((g & 1) == 0) commitA(); else commitB();
      // reissue the just-committed set for chunk g+2
      if (g < 2) {
        if ((g & 1) == 0) issueCsA(r0 * 4 + 16 * (g + 2));
        else              issueCsB(r0 * 4 + 16 * (g + 2));
      } else if (pn) {
        if ((g & 1) == 0) issueCsA(r0_1 * 4 + 16 * (g - 2));
        else              issueCsB(r0_1 * 4 + 16 * (g - 2));
      }
      // issue m for chunk g+1 into opposite-parity set
      if (g < 3)      issueM(((g & 1) == 0) ? MB : MA, r0, g + 1);
      else if (pn)    issueM(MA, r0_1, 0);
      // compute chunk g (consumes M[g&1])
      attnBody(r0, g, ((g & 1) == 0) ? MA : MB);
    }

    // ============ fc1: cat(x,u,1) [16x96] @ W1T ============
    f32x4 hac[4] = {{0.f,0.f,0.f,0.f},{0.f,0.f,0.f,0.f},{0.f,0.f,0.f,0.f},{0.f,0.f,0.f,0.f}};
    {
      f16x8 a0 = packA2(xva, xvb);
      f16x8 a1 = packA2(xvc, xvd);
      // t = 2: k = 64..95 -> u part (lq 0,1) + bias-one (k==80) + zeros
      float f[8];
      float uf[8] = {uva.x, uva.y, uva.z, uva.w, uvb.x, uvb.y, uvb.z, uvb.w};
#pragma unroll
      for (int e = 0; e < 8; ++e) {
        int k = 64 + lq * 8 + e;
        f[e] = (k < 80) ? ((lq < 2) ? uf[e] : 0.f) : (k == 80 ? 1.f : 0.f);
      }
      f16x8 a2f = packA(f);
      // x/u regs consumed -> issue next tile's x/u now (hidden under fc1..fc3)
      if (pn) issueXU(r0_1);
#pragma unroll
      for (int fi = 0; fi < 4; ++fi) hac[fi] = mf(a0, ldB(FC1_OFF + fi * 512), hac[fi]);
#pragma unroll
      for (int fi = 0; fi < 4; ++fi) hac[fi] = mf(a1, ldB(FC1_OFF + (4 + fi) * 512), hac[fi]);
#pragma unroll
      for (int fi = 0; fi < 4; ++fi) hac[fi] = mf(a2f, ldB(FC1_OFF + (8 + fi) * 512), hac[fi]);
    }
    // L2 normalize rows of h1, tanh, stash to ht cols 0..63
    {
      float rn[4];
#pragma unroll
      for (int reg = 0; reg < 4; ++reg) {
        float s = hac[0][reg] * hac[0][reg];
        s = fmaf(hac[1][reg], hac[1][reg], s);
        s = fmaf(hac[2][reg], hac[2][reg], s);
        s = fmaf(hac[3][reg], hac[3][reg], s);
        s += __shfl_xor(s, 1);
        s += __shfl_xor(s, 2);
        s += __shfl_xor(s, 4);
        s += __shfl_xor(s, 8);
        rn[reg] = __builtin_amdgcn_rcpf(fmaxf(sqrtf(s), 1e-12f));
      }
#pragma unroll
      for (int fi = 0; fi < 4; ++fi)
#pragma unroll
        for (int reg = 0; reg < 4; ++reg)
          ht[(4 * lq + reg) * HT_LD + lm + 16 * fi] =
              (__fp16)fast_tanh(hac[fi][reg] * rn[reg]);
    }

    // ============ fc2: [16x96] @ W2T + b2, tanh ============
    {
      f32x4 ac2[4] = {{0.f,0.f,0.f,0.f},{0.f,0.f,0.f,0.f},{0.f,0.f,0.f,0.f},{0.f,0.f,0.f,0.f}};
      f16x8 a2[3];
#pragma unroll
      for (int tt = 0; tt < 3; ++tt)
        a2[tt] = *reinterpret_cast<const f16x8*>(ht + lm * HT_LD + tt * 32 + lq * 8);
#pragma unroll
      for (int tt = 0; tt < 3; ++tt)
#pragma unroll
        for (int fi = 0; fi < 4; ++fi)
          ac2[fi] = mf(a2[tt], ldB(FC2_OFF + (tt * 4 + fi) * 512), ac2[fi]);
      // h2t aliases csw — attention reads complete (DS in-order per wave)
#pragma unroll
      for (int fi = 0; fi < 4; ++fi) {
        float bv = b2[lm + 16 * fi];
#pragma unroll
        for (int reg = 0; reg < 4; ++reg)
          h2t[(4 * lq + reg) * H2_LD + lm + 16 * fi] =
              (__fp16)fast_tanh(ac2[fi][reg] + bv);
      }
    }

    // ============ fc3: [16x64] @ W3T + b3, L2 norm, store ============
    {
      f32x4 o[2] = {{0.f,0.f,0.f,0.f},{0.f,0.f,0.f,0.f}};
      f16x8 a3[2];
#pragma unroll
      for (int tt = 0; tt < 2; ++tt)
        a3[tt] = *reinterpret_cast<const f16x8*>(h2t + lm * H2_LD + tt * 32 + lq * 8);
#pragma unroll
      for (int tt = 0; tt < 2; ++tt)
#pragma unroll
        for (int fi = 0; fi < 2; ++fi)
          o[fi] = mf(a3[tt], ldB(FC3_OFF + (tt * 2 + fi) * 512), o[fi]);
#pragma unroll
      for (int fi = 0; fi < 2; ++fi) {
        float bv = b3[lm + 16 * fi];
#pragma unroll
        for (int reg = 0; reg < 4; ++reg) o[fi][reg] += bv;
      }
      float rn2[4];
#pragma unroll
      for (int reg = 0; reg < 4; ++reg) {
        float s = fmaf(o[0][reg], o[0][reg], o[1][reg] * o[1][reg]);
        s += __shfl_xor(s, 1);
        s += __shfl_xor(s, 2);
        s += __shfl_xor(s, 4);
        s += __shfl_xor(s, 8);
        rn2[reg] = __builtin_amdgcn_rcpf(fmaxf(sqrtf(s), 1e-12f));
      }
#pragma unroll
      for (int fi = 0; fi < 2; ++fi)
#pragma unroll
        for (int reg = 0; reg < 4; ++reg)
          out[(size_t)(r0 + 4 * lq + reg) * MSG + lm + 16 * fi] =
              o[fi][reg] * rn2[reg];
    }
  }
}

extern "C" void kernel_launch(void* const* d_in, const int* in_sizes, int n_in,
                              void* d_out, int out_size, void* d_ws, size_t ws_size,
                              hipStream_t stream) {
  const float* x  = (const float*)d_in[0];
  const float* u  = (const float*)d_in[1];
  const float* cs = (const float*)d_in[2];
  const float* m  = (const float*)d_in[3];
  const float* W1 = (const float*)d_in[4];
  const float* b1 = (const float*)d_in[5];
  const float* W2 = (const float*)d_in[6];
  const float* b2 = (const float*)d_in[7];
  const float* W3 = (const float*)d_in[8];
  const float* b3 = (const float*)d_in[9];
  const float* Wa = (const float*)d_in[10];
  const float* ba = (const float*)d_in[11];
  float* out = (float*)d_out;
  ushort* wsf = (ushort*)d_ws;

  const int n = in_sizes[0] / S;  // batch rows
  const int tiles = (n + 15) / 16;

  hipLaunchKernelGGL(prep_pack, dim3((WS_ELEMS + 255) / 256), dim3(256), 0, stream,
                     W1, b1, Wa, ba, W2, W3, wsf);

  // persistent: each wave handles up to 2 tiles (tbase, tbase + gridDim*4)
  const int blocks = (tiles + 7) / 8;
  hipLaunchKernelGGL(critic_mfma_kernel, dim3(blocks), dim3(256), 0, stream,
                     x, u, cs, m, b2, b3, wsf, out, n);
}

// Round 10
// 220.645 us; speedup vs baseline: 1.1932x; 1.1932x over previous
//
#include <hip/hip_runtime.h>
#include <cstddef>

typedef __fp16 f16x8 __attribute__((ext_vector_type(8)));
typedef float f32x4 __attribute__((ext_vector_type(4)));
typedef unsigned int uint32;
typedef unsigned short ushort;

constexpr int S = 64, MSG = 32, CH = 73;

// frag-linear f16 weight tiles in ws. One tile = 16 cols x 32 k = 64 lanes x 8 f16.
constexpr int FC1_OFF = 0;          // 12 tiles (t0..2 x f0..3)  K=96 (80 real + bias@80)
constexpr int ATT_OFF = 12 * 512;   // 6 tiles  (t0..2 x f0..1)  K=96 (73 real + bias@73)
constexpr int FC2_OFF = 18 * 512;   // 12 tiles (t0..2 x f0..3)  K=96 exact (bias separate)
constexpr int FC3_OFF = 30 * 512;   // 4 tiles  (t0..1 x f0..1)  K=64 exact (bias separate)
constexpr int WS_ELEMS = 34 * 512;  // 17408 ushort = 34816 B

__global__ void prep_pack(const float* __restrict__ W1, const float* __restrict__ b1,
                          const float* __restrict__ Wa, const float* __restrict__ ba,
                          const float* __restrict__ W2, const float* __restrict__ W3,
                          ushort* __restrict__ wsf) {
  int idx = blockIdx.x * 256 + threadIdx.x;
  if (idx >= WS_ELEMS) return;
  int tile = idx >> 9;
  int lane = (idx >> 3) & 63;
  int e = idx & 7;
  int jloc = lane & 15;
  int kloc = ((lane >> 4) << 3) + e;  // B-frag: lane holds B[k][col=lane&15], k=(lane>>4)*8+e
  float v = 0.f;
  if (tile < 12) {                       // W1 [64][80]
    int t = tile >> 2, f = tile & 3;
    int j = f * 16 + jloc, k = t * 32 + kloc;
    v = (k < 80) ? W1[j * 80 + k] : (k == 80 ? b1[j] : 0.f);
  } else if (tile < 18) {                // Wa [32][73]
    int q = tile - 12, t = q >> 1, f = q & 1;
    int j = f * 16 + jloc, k = t * 32 + kloc;
    v = (k < 73) ? Wa[j * 73 + k] : (k == 73 ? ba[j] : 0.f);
  } else if (tile < 30) {                // W2 [64][96]
    int q = tile - 18, t = q >> 2, f = q & 3;
    int j = f * 16 + jloc, k = t * 32 + kloc;
    v = W2[j * 96 + k];
  } else {                               // W3 [32][64]
    int q = tile - 30, t = q >> 1, f = q & 1;
    int j = f * 16 + jloc, k = t * 32 + kloc;
    v = W3[j * 64 + k];
  }
  union { __fp16 h; ushort s; } cv;
  cv.h = (__fp16)v;
  wsf[idx] = cv.s;
}

__device__ __forceinline__ f32x4 mf(f16x8 a, f16x8 b, f32x4 c) {
  return __builtin_amdgcn_mfma_f32_16x16x32_f16(a, b, c, 0, 0, 0);
}
__device__ __forceinline__ uint32 pku(float a, float b) {
  auto r = __builtin_amdgcn_cvt_pkrtz(a, b);
  union { decltype(r) f; uint32 u; } v; v.f = r; return v.u;
}
__device__ __forceinline__ f16x8 packA(const float* f) {
  union { uint32 u[4]; f16x8 h; } r;
  r.u[0] = pku(f[0], f[1]); r.u[1] = pku(f[2], f[3]);
  r.u[2] = pku(f[4], f[5]); r.u[3] = pku(f[6], f[7]);
  return r.h;
}
__device__ __forceinline__ f16x8 packA2(float4 a, float4 b) {
  union { uint32 u[4]; f16x8 h; } r;
  r.u[0] = pku(a.x, a.y); r.u[1] = pku(a.z, a.w);
  r.u[2] = pku(b.x, b.y); r.u[3] = pku(b.z, b.w);
  return r.h;
}
__device__ __forceinline__ float fast_tanh(float v) {
  v = fminf(15.f, fmaxf(-15.f, v));
  float t = __expf(2.f * v);
  return (t - 1.f) * __builtin_amdgcn_rcpf(t + 1.f);
}

// direct global->LDS DMA, 16B per lane; lds dst = uniform base + lane*16
__device__ __forceinline__ void gload16(const float* g, void* l) {
  __builtin_amdgcn_global_load_lds(
      (const __attribute__((address_space(1))) void*)g,
      (__attribute__((address_space(3))) void*)l, 16, 0, 0);
}

constexpr int HT_LD = 104;  // f16 stride; 208 B (16B-aligned rows)
constexpr int H2_LD = 72;   // f16 stride; 144 B
constexpr int HBUF_B = 3328;            // 16 x 104 x 2
constexpr int CS_B = 4672;              // one 16-att-row chunk
constexpr int CSA_OFF = 4 * HBUF_B;     // 13312
constexpr int CSB_OFF = CSA_OFF + 4 * CS_B;  // 32000
constexpr int SMEM_B = CSB_OFF + 4 * CS_B;   // 50688

__launch_bounds__(256)
__global__ void critic_mfma_kernel(
    const float* __restrict__ x, const float* __restrict__ u,
    const float* __restrict__ cs, const float* __restrict__ m,
    const float* __restrict__ b2, const float* __restrict__ b3,
    const ushort* __restrict__ wsf, float* __restrict__ out, int n) {
  __shared__ __attribute__((aligned(16))) unsigned char smem[SMEM_B];

  const int wave = threadIdx.x >> 6;
  const int lane = threadIdx.x & 63;
  const int lm = lane & 15;
  const int lq = lane >> 4;
  const int r0 = (blockIdx.x * 4 + wave) * 16;  // this wave's 16 rows
  if (r0 >= n) return;                          // no barriers anywhere -> safe

  __fp16* __restrict__ ht = reinterpret_cast<__fp16*>(smem + wave * HBUF_B);
  unsigned char* __restrict__ csAb = smem + CSA_OFF + wave * CS_B;
  unsigned char* __restrict__ csBb = smem + CSB_OFF + wave * CS_B;
  const float* __restrict__ csAf = reinterpret_cast<const float*>(csAb);
  const float* __restrict__ csBf = reinterpret_cast<const float*>(csBb);
  __fp16* __restrict__ h2t = reinterpret_cast<__fp16*>(csAb);  // union after attn

  auto ldB = [&](int off_tile) -> f16x8 {
    return *reinterpret_cast<const f16x8*>(wsf + off_tile + lane * 8);
  };

  // chunk DMA: 16 contiguous att-rows = 4672 B (4x64 + 36 lanes x 16B)
  auto gloadChunk = [&](int row16, unsigned char* buf) {
    const float* sl = cs + (size_t)row16 * CH + lane * 4;
    gload16(sl,        buf);
    gload16(sl + 256,  buf + 1024);
    gload16(sl + 512,  buf + 2048);
    gload16(sl + 768,  buf + 3072);
    if (lane < 36) gload16(sl + 1024, buf + 4096);
  };
  float MA[8], MB[8];
  auto issueM = [&](float* MR, int g) {
    const float* __restrict__ mrow = m + (size_t)(r0 + 4 * g + lq) * 128;
#pragma unroll
    for (int c = 0; c < 4; ++c) {
      MR[c * 2 + 0] = mrow[c * 32 + lm];
      MR[c * 2 + 1] = mrow[c * 32 + lm + 16];
    }
  };

  // ---- prologue: order-pinned issue groups (counts feed hand vmcnt below) ----
  f16x8 wa[6];
#pragma unroll
  for (int i = 0; i < 6; ++i) wa[i] = ldB(ATT_OFF + i * 512);  // 6 vmem
  __builtin_amdgcn_sched_barrier(0);
  const float4* __restrict__ xrow4 =
      reinterpret_cast<const float4*>(x + (size_t)(r0 + lm) * S);
  float4 xva = xrow4[2 * lq], xvb = xrow4[2 * lq + 1];
  float4 xvc = xrow4[8 + 2 * lq], xvd = xrow4[9 + 2 * lq];
  const int uq = (lq < 2) ? lq : 0;
  const float4* __restrict__ urow4 =
      reinterpret_cast<const float4*>(u + (size_t)(r0 + lm) * 16);
  float4 uva = urow4[2 * uq], uvb = urow4[2 * uq + 1];  // 6 vmem
  __builtin_amdgcn_sched_barrier(0);
  gloadChunk(r0 * 4, csAb);            // 5 vmem  (chunk 0)
  __builtin_amdgcn_sched_barrier(0);
  issueM(MA, 0);                       // 8 vmem  (m for chunk 0)
  __builtin_amdgcn_sched_barrier(0);
  gloadChunk(r0 * 4 + 16, csBb);       // 5 vmem  (chunk 1)
  __builtin_amdgcn_sched_barrier(0);

  // ============ Attention: 4 chunks, depth-2 LDS-DMA pipeline ============
#pragma unroll
  for (int g = 0; g < 4; ++g) {
    // ensure chunk g's DMA landed: leaves m(g) 8 + next gload 5 in flight
    if (g == 3) { asm volatile("s_waitcnt vmcnt(8)" ::: "memory"); }
    else        { asm volatile("s_waitcnt vmcnt(13)" ::: "memory"); }
    __builtin_amdgcn_sched_barrier(0);

    const float* __restrict__ crow = ((g & 1) ? csBf : csAf) + lm * CH;
    f32x4 zac[2] = {{0.f, 0.f, 0.f, 0.f}, {0.f, 0.f, 0.f, 0.f}};
#pragma unroll
    for (int tt = 0; tt < 3; ++tt) {
      float f[8];
      const int kbase = tt * 32 + lq * 8;
#pragma unroll
      for (int e = 0; e < 8; ++e) {
        int k = kbase + e;
        f[e] = (k < 73) ? crow[k] : (k == 73 ? 1.f : 0.f);
      }
      f16x8 af = packA(f);
      zac[0] = mf(af, wa[tt * 2 + 0], zac[0]);
      zac[1] = mf(af, wa[tt * 2 + 1], zac[1]);
    }
    // chunk g's LDS reads retired -> its buffer is free for chunk g+2
    asm volatile("s_waitcnt lgkmcnt(0)" ::: "memory");
    __builtin_amdgcn_sched_barrier(0);
    if (g < 2) gloadChunk(r0 * 4 + 16 * (g + 2), (g & 1) ? csBb : csAb);  // 5 vmem
    __builtin_amdgcn_sched_barrier(0);
    if (g < 3) issueM((g & 1) ? MA : MB, g + 1);  // 8 vmem, opposite parity set
    __builtin_amdgcn_sched_barrier(0);

    // softmax (lane-local; consumes M[g&1] -> compiler-counted wait)
    const float* MR = (g & 1) ? MB : MA;
#pragma unroll
    for (int f = 0; f < 2; ++f) {
      const int j = lm + 16 * f;
      float e0 = __expf(zac[f][0]);
      float e1 = __expf(zac[f][1]);
      float e2 = __expf(zac[f][2]);
      float e3 = __expf(zac[f][3]);
      float den = (e0 + e1) + (e2 + e3);
      float num = fmaf(MR[0 + f], e0,
                  fmaf(MR[2 + f], e1,
                  fmaf(MR[4 + f], e2, MR[6 + f] * e3)));
      float mg = num * __builtin_amdgcn_rcpf(den);
      ht[(4 * g + lq) * HT_LD + 64 + j] = (__fp16)fast_tanh(mg);
    }
  }

  // ============ fc1: cat(x,u,1) [16x96] @ W1T ============
  f32x4 hac[4] = {{0.f,0.f,0.f,0.f},{0.f,0.f,0.f,0.f},{0.f,0.f,0.f,0.f},{0.f,0.f,0.f,0.f}};
  {
    f16x8 a0 = packA2(xva, xvb);
    f16x8 a1 = packA2(xvc, xvd);
    float f[8];
    float uf[8] = {uva.x, uva.y, uva.z, uva.w, uvb.x, uvb.y, uvb.z, uvb.w};
#pragma unroll
    for (int e = 0; e < 8; ++e) {
      int k = 64 + lq * 8 + e;
      f[e] = (k < 80) ? ((lq < 2) ? uf[e] : 0.f) : (k == 80 ? 1.f : 0.f);
    }
    f16x8 a2f = packA(f);
#pragma unroll
    for (int fi = 0; fi < 4; ++fi) hac[fi] = mf(a0, ldB(FC1_OFF + fi * 512), hac[fi]);
#pragma unroll
    for (int fi = 0; fi < 4; ++fi) hac[fi] = mf(a1, ldB(FC1_OFF + (4 + fi) * 512), hac[fi]);
#pragma unroll
    for (int fi = 0; fi < 4; ++fi) hac[fi] = mf(a2f, ldB(FC1_OFF + (8 + fi) * 512), hac[fi]);
  }
  // L2 normalize rows of h1, tanh, stash to ht cols 0..63
  {
    float rn[4];
#pragma unroll
    for (int reg = 0; reg < 4; ++reg) {
      float s = hac[0][reg] * hac[0][reg];
      s = fmaf(hac[1][reg], hac[1][reg], s);
      s = fmaf(hac[2][reg], hac[2][reg], s);
      s = fmaf(hac[3][reg], hac[3][reg], s);
      s += __shfl_xor(s, 1);
      s += __shfl_xor(s, 2);
      s += __shfl_xor(s, 4);
      s += __shfl_xor(s, 8);
      rn[reg] = __builtin_amdgcn_rcpf(fmaxf(sqrtf(s), 1e-12f));
    }
#pragma unroll
    for (int fi = 0; fi < 4; ++fi)
#pragma unroll
      for (int reg = 0; reg < 4; ++reg)
        ht[(4 * lq + reg) * HT_LD + lm + 16 * fi] =
            (__fp16)fast_tanh(hac[fi][reg] * rn[reg]);
  }

  // ============ fc2: [16x96] @ W2T + b2, tanh ============
  {
    f32x4 ac2[4] = {{0.f,0.f,0.f,0.f},{0.f,0.f,0.f,0.f},{0.f,0.f,0.f,0.f},{0.f,0.f,0.f,0.f}};
    f16x8 a2[3];
#pragma unroll
    for (int tt = 0; tt < 3; ++tt)
      a2[tt] = *reinterpret_cast<const f16x8*>(ht + lm * HT_LD + tt * 32 + lq * 8);
#pragma unroll
    for (int tt = 0; tt < 3; ++tt)
#pragma unroll
      for (int fi = 0; fi < 4; ++fi)
        ac2[fi] = mf(a2[tt], ldB(FC2_OFF + (tt * 4 + fi) * 512), ac2[fi]);
    // h2t aliases csA — all attention reads retired (lgkmcnt(0) in loop)
#pragma unroll
    for (int fi = 0; fi < 4; ++fi) {
      float bv = b2[lm + 16 * fi];
#pragma unroll
      for (int reg = 0; reg < 4; ++reg)
        h2t[(4 * lq + reg) * H2_LD + lm + 16 * fi] =
            (__fp16)fast_tanh(ac2[fi][reg] + bv);
    }
  }

  // ============ fc3: [16x64] @ W3T + b3, L2 norm, store ============
  {
    f32x4 o[2] = {{0.f,0.f,0.f,0.f},{0.f,0.f,0.f,0.f}};
    f16x8 a3[2];
#pragma unroll
    for (int tt = 0; tt < 2; ++tt)
      a3[tt] = *reinterpret_cast<const f16x8*>(h2t + lm * H2_LD + tt * 32 + lq * 8);
#pragma unroll
    for (int tt = 0; tt < 2; ++tt)
#pragma unroll
      for (int fi = 0; fi < 2; ++fi)
        o[fi] = mf(a3[tt], ldB(FC3_OFF + (tt * 2 + fi) * 512), o[fi]);
#pragma unroll
    for (int fi = 0; fi < 2; ++fi) {
      float bv = b3[lm + 16 * fi];
#pragma unroll
      for (int reg = 0; reg < 4; ++reg) o[fi][reg] += bv;
    }
    float rn2[4];
#pragma unroll
    for (int reg = 0; reg < 4; ++reg) {
      float s = fmaf(o[0][reg], o[0][reg], o[1][reg] * o[1][reg]);
      s += __shfl_xor(s, 1);
      s += __shfl_xor(s, 2);
      s += __shfl_xor(s, 4);
      s += __shfl_xor(s, 8);
      rn2[reg] = __builtin_amdgcn_rcpf(fmaxf(sqrtf(s), 1e-12f));
    }
#pragma unroll
    for (int fi = 0; fi < 2; ++fi)
#pragma unroll
      for (int reg = 0; reg < 4; ++reg)
        out[(size_t)(r0 + 4 * lq + reg) * MSG + lm + 16 * fi] =
            o[fi][reg] * rn2[reg];
  }
}

extern "C" void kernel_launch(void* const* d_in, const int* in_sizes, int n_in,
                              void* d_out, int out_size, void* d_ws, size_t ws_size,
                              hipStream_t stream) {
  const float* x  = (const float*)d_in[0];
  const float* u  = (const float*)d_in[1];
  const float* cs = (const float*)d_in[2];
  const float* m  = (const float*)d_in[3];
  const float* W1 = (const float*)d_in[4];
  const float* b1 = (const float*)d_in[5];
  const float* W2 = (const float*)d_in[6];
  const float* b2 = (const float*)d_in[7];
  const float* W3 = (const float*)d_in[8];
  const float* b3 = (const float*)d_in[9];
  const float* Wa = (const float*)d_in[10];
  const float* ba = (const float*)d_in[11];
  float* out = (float*)d_out;
  ushort* wsf = (ushort*)d_ws;

  const int n = in_sizes[0] / S;  // batch rows

  hipLaunchKernelGGL(prep_pack, dim3((WS_ELEMS + 255) / 256), dim3(256), 0, stream,
                     W1, b1, Wa, ba, W2, W3, wsf);

  const int blocks = (n + 63) / 64;  // 64 rows per block (4 waves x 16), 1 tile/wave
  hipLaunchKernelGGL(critic_mfma_kernel, dim3(blocks), dim3(256), 0, stream,
                     x, u, cs, m, b2, b3, wsf, out, n);
}